// Round 27
// baseline (134.350 us; speedup 1.0000x reference)
//
#include <hip/hip_runtime.h>
#include <hip/hip_bf16.h>

// Problem constants
#define NB    2048   // batch
#define SS    200    // seq len
#define DSEQ  256
#define DITEM 64
#define AA    128    // attn dim (H=1, HD=128)
#define NS    4      // batch rows (streams) per block in kernel A
#define MAXNT 13

typedef __bf16 bf16x8 __attribute__((ext_vector_type(8)));
typedef __bf16 bf16x4 __attribute__((ext_vector_type(4)));
typedef float  f32x4  __attribute__((ext_vector_type(4)));

__device__ __forceinline__ float prelu_f(float x, float a) { return x >= 0.f ? x : a * x; }

// 16-lane sum via DPP row_ror — VALU pipe only; result valid in all 16 lanes.
#define ROR_F(x, n) __int_as_float(__builtin_amdgcn_update_dpp(0, __float_as_int(x), 0x120 + (n), 0xf, 0xf, true))
__device__ __forceinline__ float row_sum16(float x) {
    x += ROR_F(x, 1); x += ROR_F(x, 2); x += ROR_F(x, 4); x += ROR_F(x, 8);
    return x;
}

// ---------------- prep: W_k|W_v -> bf16 [256 rows][512B], XOR-swizzled within rows
__global__ void prep_kernel(const float* __restrict__ Wk, const float* __restrict__ Wv,
                            __hip_bfloat16* __restrict__ Wb) {
    int idx = blockIdx.x * 256 + threadIdx.x;   // 256 blocks -> 65536
    int a = idx >> 8, d = idx & 255;
    float v = (a < 128) ? Wk[a * 256 + d] : Wv[(a - 128) * 256 + d];
    int boff = (d * 2) ^ ((a & 7) << 4);
    Wb[a * 256 + (boff >> 1)] = __float2bfloat16(v);
}

// gather-staging: row index from the compacted idx list
#define ISSUE_R(tt, s, L, H)                                                    \
    {                                                                           \
        int r_ = idx_lds[s][(tt) * 16 + srow];                                  \
        const float* xp_ = X + ((size_t)(b0 + (s)) * SS + r_) * DSEQ + chunk * 8; \
        L = *reinterpret_cast<const f32x4*>(xp_);                               \
        H = *reinterpret_cast<const f32x4*>(xp_ + 4);                           \
    }

#define STAGE_R(tt, s, L, H)                                                    \
    {                                                                           \
        bf16x8 v_;                                                              \
        v_[0] = (__bf16)L[0]; v_[1] = (__bf16)L[1];                             \
        v_[2] = (__bf16)L[2]; v_[3] = (__bf16)L[3];                             \
        v_[4] = (__bf16)H[0]; v_[5] = (__bf16)H[1];                             \
        v_[6] = (__bf16)H[2]; v_[7] = (__bf16)H[3];                             \
        *reinterpret_cast<bf16x8*>(xbase + (s) * 16384 + ((tt) & 1) * 8192 + wr_off) = v_; \
    }

// fused half-compute over k = k0..k0+3: weights loaded ONCE, used by all 4 streams
#define CHALF(k0)                                                               \
    _Pragma("unroll")                                                           \
    for (int k = (k0); k < (k0) + 4; k++) {                                     \
        const int o = (k * 64 + rg * 16) ^ rswz;                                \
        bf16x8 bk  = *reinterpret_cast<const bf16x8*>(kb + o);                  \
        bf16x8 bv  = *reinterpret_cast<const bf16x8*>(vb + o);                  \
        bf16x8 af0 = *reinterpret_cast<const bf16x8*>(rb0 + o);                 \
        bf16x8 af1 = *reinterpret_cast<const bf16x8*>(rb1 + o);                 \
        bf16x8 af2 = *reinterpret_cast<const bf16x8*>(rb2 + o);                 \
        bf16x8 af3 = *reinterpret_cast<const bf16x8*>(rb3 + o);                 \
        aK0 = __builtin_amdgcn_mfma_f32_16x16x32_bf16(af0, bk, aK0, 0, 0, 0);   \
        aV0 = __builtin_amdgcn_mfma_f32_16x16x32_bf16(af0, bv, aV0, 0, 0, 0);   \
        aK1 = __builtin_amdgcn_mfma_f32_16x16x32_bf16(af1, bk, aK1, 0, 0, 0);   \
        aV1 = __builtin_amdgcn_mfma_f32_16x16x32_bf16(af1, bv, aV1, 0, 0, 0);   \
        aK2 = __builtin_amdgcn_mfma_f32_16x16x32_bf16(af2, bk, aK2, 0, 0, 0);   \
        aV2 = __builtin_amdgcn_mfma_f32_16x16x32_bf16(af2, bv, aV2, 0, 0, 0);   \
        aK3 = __builtin_amdgcn_mfma_f32_16x16x32_bf16(af3, bk, aK3, 0, 0, 0);   \
        aV3 = __builtin_amdgcn_mfma_f32_16x16x32_bf16(af3, bv, aV3, 0, 0, 0);   \
    }

#define SCOREPART(tt, s)                                                        \
    {                                                                           \
        float pr_[4];                                                           \
        _Pragma("unroll")                                                       \
        for (int i = 0; i < 4; i++) pr_[i] = row_sum16(prelu_f(aK##s[i], pa) * uw##s); \
        if (c == 0) {                                                           \
            _Pragma("unroll")                                                   \
            for (int i = 0; i < 4; i++) sp[s][(tt) & 1][rg * 4 + i][w] = pr_[i]; \
        }                                                                       \
    }

// pack prelu'd V for stream s, tile t -> ws  (R15-verified layout)
#define VSTORE(tt, s)                                                           \
    {                                                                           \
        bf16x4 vv_;                                                             \
        vv_[0] = (__bf16)prelu_f(aV##s[0], pa);                                 \
        vv_[1] = (__bf16)prelu_f(aV##s[1], pa);                                 \
        vv_[2] = (__bf16)prelu_f(aV##s[2], pa);                                 \
        vv_[3] = (__bf16)prelu_f(aV##s[3], pa);                                 \
        *reinterpret_cast<bf16x4*>(Vbuf + ((size_t)(b0 + (s)) * MAXNT + (tt)) * 4096 \
                                   + w * 512 + lane * 8) = vv_;                 \
    }

// deferred wave-parallel score sum of tile tp: wave s (<4) handles stream s
#define SCSUM(tp)                                                               \
    if (w < NS && lane < 16) {                                                  \
        const int q_ = (tp) & 1;                                                \
        f32x4 r0_ = *reinterpret_cast<const f32x4*>(&sp[w][q_][lane][0]);       \
        f32x4 r1_ = *reinterpret_cast<const f32x4*>(&sp[w][q_][lane][4]);       \
        scores_ws[(size_t)(b0 + w) * 208 + (tp) * 16 + lane] =                  \
            r0_[0]+r0_[1]+r0_[2]+r0_[3]+r1_[0]+r1_[1]+r1_[2]+r1_[3];            \
    }

// ---------------- kernel A: projection only (no softmax state in the loop)
__global__ __launch_bounds__(512, 2)
void proj_a(
    const float* __restrict__ X,      // [2048,200,256]
    const int*   __restrict__ maskp,  // [2048,200] 1 = pad
    const float* __restrict__ temb,   // [2048,64]
    const float* __restrict__ Wq,     // [128,64]
    const float* __restrict__ Wker,   // [128,128]
    const float* __restrict__ prelu_a,
    const __hip_bfloat16* __restrict__ Wb,  // ws: swizzled bf16 weights
    float* __restrict__ scores_ws,    // ws: [2048][208] raw compacted scores
    char*  __restrict__ Vbuf)         // ws: [2048][13][4096] bf16 V
{
    __shared__ __hip_bfloat16 Xt[NS][2][16][256];   // 64 KB
    __shared__ float sp[NS][2][16][8];              // 4 KB
    __shared__ float arena[NS][336];                // prologue tq/Qv/uv
    __shared__ int   idx_lds[NS][208];
    __shared__ int   nvt[NS];

    const int tid  = threadIdx.x;
    const int w    = tid >> 6;        // wave 0..7
    const int lane = tid & 63;
    const int c    = lane & 15;
    const int rg   = lane >> 4;
    const int b0   = blockIdx.x * NS;
    const float pa = *prelu_a;

    const int srow  = tid >> 5;
    const int chunk = tid & 31;
    const int wr_off = srow * 512 + ((chunk * 16) ^ ((srow & 7) << 4));
    char* xbase = (char*)&Xt[0][0][0][0];
    const int rswz = (c & 7) << 4;

    const char* kb = (const char*)Wb + (size_t)(16 * w + c) * 512;
    const char* vb = kb + 65536;

    // ---- compaction (wave w handles stream w)
    if (w < NS) {
        int base = 0;
        #pragma unroll
        for (int ch = 0; ch < 4; ch++) {
            int pos = ch * 64 + lane;
            bool val = (pos < SS) && (maskp[(size_t)(b0 + w) * SS + pos] == 0);
            unsigned long long ball = __ballot(val);
            int pre = __popcll(ball & ((1ull << lane) - 1));
            if (val) idx_lds[w][base + pre] = pos;
            base += (int)__popcll(ball);
        }
        asm volatile("s_waitcnt lgkmcnt(0)" ::: "memory");
        int safe = (base > 0) ? idx_lds[w][base - 1] : 0;
        for (int j = base + lane; j < 208; j += 64) idx_lds[w][j] = safe;
        if (lane == 0) nvt[w] = base;
    }
    const int ps = tid >> 7;
    const int po = tid & 127;
    if (po < DITEM) arena[ps][po] = temb[(size_t)(b0 + ps) * DITEM + po];
    __syncthreads();

    // issue tile-0 gathers now; latency hides under Q/u
    f32x4 p0lo, p0hi, p1lo, p1hi, p2lo, p2hi, p3lo, p3hi;
    ISSUE_R(0, 0, p0lo, p0hi); ISSUE_R(0, 1, p1lo, p1hi);
    ISSUE_R(0, 2, p2lo, p2hi); ISSUE_R(0, 3, p3lo, p3hi);

    // Q = prelu(W_q @ t)
    {
        float acc = 0.f;
        #pragma unroll
        for (int d4 = 0; d4 < 16; d4++) {
            f32x4 tv = *reinterpret_cast<const f32x4*>(&arena[ps][d4 * 4]);
            f32x4 wq4 = *reinterpret_cast<const f32x4*>(Wq + (size_t)po * DITEM + d4 * 4);
            acc += wq4[0]*tv[0] + wq4[1]*tv[1] + wq4[2]*tv[2] + wq4[3]*tv[3];
        }
        arena[ps][64 + po] = prelu_f(acc, pa);
    }
    __syncthreads();

    // u = W_kernel @ Q
    {
        float acc = 0.f;
        #pragma unroll
        for (int d4 = 0; d4 < 32; d4++) {
            f32x4 qv = *reinterpret_cast<const f32x4*>(&arena[ps][64 + d4 * 4]);
            f32x4 wk4 = *reinterpret_cast<const f32x4*>(Wker + (size_t)po * AA + d4 * 4);
            acc += wk4[0]*qv[0] + wk4[1]*qv[1] + wk4[2]*qv[2] + wk4[3]*qv[3];
        }
        arena[ps][192 + po] = acc;
    }
    __syncthreads();
    const float uw0 = arena[0][192 + 16 * w + c];
    const float uw1 = arena[1][192 + 16 * w + c];
    const float uw2 = arena[2][192 + 16 * w + c];
    const float uw3 = arena[3][192 + 16 * w + c];
    const int nv0 = nvt[0], nv1 = nvt[1], nv2 = nvt[2], nv3 = nvt[3];
    int ntmax = (nv0 + 15) >> 4;
    { int n1 = (nv1 + 15) >> 4; if (n1 > ntmax) ntmax = n1; }
    { int n2 = (nv2 + 15) >> 4; if (n2 > ntmax) ntmax = n2; }
    { int n3 = (nv3 + 15) >> 4; if (n3 > ntmax) ntmax = n3; }
    if (ntmax < 1) ntmax = 1;

    // stage tile 0 from long-landed prologue regs
    STAGE_R(0, 0, p0lo, p0hi); STAGE_R(0, 1, p1lo, p1hi);
    STAGE_R(0, 2, p2lo, p2hi); STAGE_R(0, 3, p3lo, p3hi);
    __syncthreads();

    f32x4 stAlo, stAhi, stBlo, stBhi;

    for (int t = 0; t < ntmax; t++) {
        const int more = (t + 1 < ntmax);

        if (more) { ISSUE_R(t + 1, 0, stAlo, stAhi); ISSUE_R(t + 1, 1, stBlo, stBhi); }

        // deferred score sum of tile t-1 (wave-parallel, no chains)
        if (t > 0) SCSUM(t - 1);

        const char* rb0 = xbase + 0 * 16384 + (t & 1) * 8192 + c * 512;
        const char* rb1 = xbase + 1 * 16384 + (t & 1) * 8192 + c * 512;
        const char* rb2 = xbase + 2 * 16384 + (t & 1) * 8192 + c * 512;
        const char* rb3 = xbase + 3 * 16384 + (t & 1) * 8192 + c * 512;
        f32x4 aK0 = {0.f,0.f,0.f,0.f}, aK1 = {0.f,0.f,0.f,0.f};
        f32x4 aK2 = {0.f,0.f,0.f,0.f}, aK3 = {0.f,0.f,0.f,0.f};
        f32x4 aV0 = {0.f,0.f,0.f,0.f}, aV1 = {0.f,0.f,0.f,0.f};
        f32x4 aV2 = {0.f,0.f,0.f,0.f}, aV3 = {0.f,0.f,0.f,0.f};

        CHALF(0);

        if (more) {
            STAGE_R(t + 1, 0, stAlo, stAhi); ISSUE_R(t + 1, 2, stAlo, stAhi);
            STAGE_R(t + 1, 1, stBlo, stBhi); ISSUE_R(t + 1, 3, stBlo, stBhi);
        }

        CHALF(4);

        SCOREPART(t, 0); SCOREPART(t, 1); SCOREPART(t, 2); SCOREPART(t, 3);
        VSTORE(t, 0); VSTORE(t, 1); VSTORE(t, 2); VSTORE(t, 3);

        if (more) { STAGE_R(t + 1, 2, stAlo, stAhi); STAGE_R(t + 1, 3, stBlo, stBhi); }
        __syncthreads();
    }

    // final score sum (sp published by last barrier)
    SCSUM(ntmax - 1);
}

// ---------------- kernel B: softmax + PV + FFN per batch row
__global__ __launch_bounds__(256)
void attn_ffn_b(
    const int*   __restrict__ maskp,
    const float* __restrict__ scores_ws,
    const char*  __restrict__ Vbuf,
    const float* __restrict__ ffnW,   // [256,128]
    const float* __restrict__ ffnb,
    const float* __restrict__ prelu_a,
    float* __restrict__ out)
{
    __shared__ int   idx[208];
    __shared__ int   inv[208];
    __shared__ int   nv_s;
    __shared__ float ebuf[208];
    __shared__ float ovec[AA];
    __shared__ float red[256];
    __shared__ float wr1[4], wr2[4];

    const int b = blockIdx.x, tid = threadIdx.x;
    const int w = tid >> 6, lane = tid & 63;
    const float pa = *prelu_a;
    const float inv_scale = 0.08838834764831845f;  // 1/sqrt(128)

    // compaction + inverse map (wave 0)
    if (w == 0) {
        int base = 0;
        #pragma unroll
        for (int ch = 0; ch < 4; ch++) {
            int pos = ch * 64 + lane;
            bool val = (pos < SS) && (maskp[(size_t)b * SS + pos] == 0);
            unsigned long long ball = __ballot(val);
            int pre = __popcll(ball & ((1ull << lane) - 1));
            if (val) { idx[base + pre] = pos; inv[pos] = base + pre; }
            base += (int)__popcll(ball);
        }
        if (lane == 0) nv_s = base;
    }
    __syncthreads();
    const int nv = nv_s;

    // softmax over nv compacted scores
    float sc = -3e38f;
    if (tid < nv) sc = scores_ws[(size_t)b * 208 + tid] * inv_scale;
    float v = sc;
    #pragma unroll
    for (int o = 1; o < 64; o <<= 1) v = fmaxf(v, __shfl_xor(v, o, 64));
    if (lane == 0) wr1[w] = v;
    __syncthreads();
    const float m = fmaxf(fmaxf(wr1[0], wr1[1]), fmaxf(wr1[2], wr1[3]));
    float e = (tid < nv) ? __expf(sc - m) : 0.f;
    if (tid < 208) ebuf[tid] = e;
    float sv = e;
    #pragma unroll
    for (int o = 1; o < 64; o <<= 1) sv += __shfl_xor(sv, o, 64);
    if (lane == 0) wr2[w] = sv;
    __syncthreads();
    const float l = wr2[0] + wr2[1] + wr2[2] + wr2[3];
    const float invl = 1.0f / l;

    // attn output: masked -> 0, valid -> e/l at original positions
    if (tid < SS) {
        int mk = maskp[(size_t)b * SS + tid];
        out[(size_t)NB * DSEQ + (size_t)b * SS + tid] = mk ? 0.f : ebuf[inv[tid]] * invl;
    }

    // PV over compacted slots (ebuf=0 kills slots >= nv)
    const int nt = (nv + 15) >> 4;
    const int a = tid & 127, h = tid >> 7;
    const int t0 = h ? (nt >> 1) : 0;
    const int t1 = h ? nt : (nt >> 1);
    const char* vbase = Vbuf + (size_t)b * MAXNT * 4096 + (a >> 4) * 512 + (a & 15) * 8;
    float acc = 0.f;
    for (int t = t0; t < t1; t++) {
        #pragma unroll
        for (int rg = 0; rg < 4; rg++) {
            bf16x4 vv = *reinterpret_cast<const bf16x4*>(vbase + (size_t)t * 4096 + rg * 128);
            const int s = t * 16 + rg * 4;
            acc += ebuf[s]     * (float)vv[0] + ebuf[s + 1] * (float)vv[1]
                 + ebuf[s + 2] * (float)vv[2] + ebuf[s + 3] * (float)vv[3];
        }
    }
    red[tid] = acc;
    __syncthreads();
    if (tid < AA) ovec[tid] = (red[tid] + red[tid + 128]) * invl;
    __syncthreads();

    // FFN
    float facc = ffnb[tid];
    #pragma unroll 8
    for (int a4 = 0; a4 < 32; a4++) {
        f32x4 ov = *reinterpret_cast<const f32x4*>(&ovec[a4 * 4]);
        f32x4 wv = *reinterpret_cast<const f32x4*>(ffnW + (size_t)tid * AA + a4 * 4);
        facc += wv[0]*ov[0] + wv[1]*ov[1] + wv[2]*ov[2] + wv[3]*ov[3];
    }
    out[(size_t)b * DSEQ + tid] = prelu_f(facc, pa);
}

extern "C" void kernel_launch(void* const* d_in, const int* in_sizes, int n_in,
                              void* d_out, int out_size, void* d_ws, size_t ws_size,
                              hipStream_t stream) {
    const float* X    = (const float*)d_in[0];
    const int*   mask = (const int*)  d_in[1];
    const float* temb = (const float*)d_in[2];
    const float* Wq   = (const float*)d_in[3];
    const float* Wk   = (const float*)d_in[4];
    const float* Wv   = (const float*)d_in[5];
    const float* Wker = (const float*)d_in[6];
    const float* ffnW = (const float*)d_in[7];
    const float* ffnb = (const float*)d_in[8];
    const float* pa   = (const float*)d_in[9];
    float* out = (float*)d_out;

    // ws layout: Wb 128KB | Vbuf 104 MB | scores 1.7 MB
    char* ws = (char*)d_ws;
    __hip_bfloat16* Wb = (__hip_bfloat16*)ws;
    char*  Vbuf      = ws + 131072;
    float* scores_ws = (float*)(ws + 131072 + (size_t)NB * MAXNT * 4096);

    prep_kernel<<<256, 256, 0, stream>>>(Wk, Wv, Wb);
    proj_a<<<NB / NS, 512, 0, stream>>>(X, mask, temb, Wq, Wker, pa, Wb, scores_ws, Vbuf);
    attn_ffn_b<<<NB, 256, 0, stream>>>(mask, scores_ws, Vbuf, ffnW, ffnb, pa, out);
}

// Round 28
// 109.797 us; speedup vs baseline: 1.2236x; 1.2236x over previous
//
#include <hip/hip_runtime.h>
#include <hip/hip_bf16.h>

// Problem constants
#define NB    2048   // batch
#define SS    200    // seq len
#define DSEQ  256
#define DITEM 64
#define AA    128    // attn dim (H=1, HD=128)
#define NS    4      // batch rows (streams) per block

typedef __bf16 bf16x8 __attribute__((ext_vector_type(8)));
typedef float  f32x4  __attribute__((ext_vector_type(4)));

__device__ __forceinline__ float prelu_f(float x, float a) { return x >= 0.f ? x : a * x; }

// 16-lane reduce via DPP row_ror — VALU pipe only; result valid in all 16 lanes.
#define ROR_F(x, n) __int_as_float(__builtin_amdgcn_update_dpp(0, __float_as_int(x), 0x120 + (n), 0xf, 0xf, true))
__device__ __forceinline__ float row_sum16(float x) {
    x += ROR_F(x, 1); x += ROR_F(x, 2); x += ROR_F(x, 4); x += ROR_F(x, 8);
    return x;
}
__device__ __forceinline__ float row_max16(float x) {
    x = fmaxf(x, ROR_F(x, 1)); x = fmaxf(x, ROR_F(x, 2));
    x = fmaxf(x, ROR_F(x, 4)); x = fmaxf(x, ROR_F(x, 8));
    return x;
}

// ---------------- prep: W_k|W_v -> bf16 [256 rows][512B], XOR-swizzled within rows
__global__ void prep_kernel(const float* __restrict__ Wk, const float* __restrict__ Wv,
                            __hip_bfloat16* __restrict__ Wb) {
    int idx = blockIdx.x * 256 + threadIdx.x;   // 256 blocks -> 65536
    int a = idx >> 8, d = idx & 255;
    float v = (a < 128) ? Wk[a * 256 + d] : Wv[(a - 128) * 256 + d];
    int boff = (d * 2) ^ ((a & 7) << 4);
    Wb[a * 256 + (boff >> 1)] = __float2bfloat16(v);
}

// gather-staging: row index from the compacted idx list
#define ISSUE_R(tt, s, L, H)                                                    \
    {                                                                           \
        int r_ = idx_lds[s][(tt) * 16 + srow];                                  \
        const float* xp_ = X + ((size_t)(b0 + (s)) * SS + r_) * DSEQ + chunk * 8; \
        L = *reinterpret_cast<const f32x4*>(xp_);                               \
        H = *reinterpret_cast<const f32x4*>(xp_ + 4);                           \
    }

#define STAGE_R(tt, s, L, H)                                                    \
    {                                                                           \
        bf16x8 v_;                                                              \
        v_[0] = (__bf16)L[0]; v_[1] = (__bf16)L[1];                             \
        v_[2] = (__bf16)L[2]; v_[3] = (__bf16)L[3];                             \
        v_[4] = (__bf16)H[0]; v_[5] = (__bf16)H[1];                             \
        v_[6] = (__bf16)H[2]; v_[7] = (__bf16)H[3];                             \
        *reinterpret_cast<bf16x8*>(xbase + (s) * 16384 + ((tt) & 1) * 8192 + wr_off) = v_; \
    }

// deferred online-softmax + V-fold of COMPACTED tile `tp`, stream s.
// EXACT defer-max: when tmax <= m (wave-uniform), rescale is the identity
// (nm=m, fs=1) — skip the expf and the l/oacc rescale entirely.
#define SMFOLD(tp, s)                                                           \
    {                                                                           \
        const int q_ = (tp) & 1;                                                \
        const int s0_ = (tp) * 16;                                              \
        f32x4 r0_ = *reinterpret_cast<const f32x4*>(&sp[s][q_][c][0]);          \
        f32x4 r1_ = *reinterpret_cast<const f32x4*>(&sp[s][q_][c][4]);          \
        float sc_ = (r0_[0]+r0_[1]+r0_[2]+r0_[3]+r1_[0]+r1_[1]+r1_[2]+r1_[3]) * inv_scale; \
        sc_ = (s0_ + c < nv##s) ? sc_ : -1e9f;                                  \
        if (tid < 16 && s0_ + tid < nv##s) arena[s][idx_lds[s][s0_ + tid]] = sc_; \
        float tmax_ = row_max16(sc_);                                           \
        if (tmax_ > m##s) {                                                     \
            float fs_ = __expf(m##s - tmax_);                                   \
            l##s *= fs_; oacc##s *= fs_; m##s = tmax_;                          \
        }                                                                       \
        float e_  = __expf(sc_ - m##s);                                         \
        l##s += row_sum16(e_);                                                  \
        _Pragma("unroll")                                                       \
        for (int i_ = 0; i_ < 4; i_++) {                                        \
            float ew_ = __shfl(e_, (lane & 48) | (rg * 4 + i_), 64);            \
            oacc##s += ew_ * prelu_f(aVp##s[i_], pa);                           \
        }                                                                       \
    }

// fused half-compute over k = k0..k0+3: weights loaded ONCE, used by all 4 streams
#define CHALF(k0)                                                               \
    _Pragma("unroll")                                                           \
    for (int k = (k0); k < (k0) + 4; k++) {                                     \
        const int o = (k * 64 + rg * 16) ^ rswz;                                \
        bf16x8 bk  = *reinterpret_cast<const bf16x8*>(kb + o);                  \
        bf16x8 bv  = *reinterpret_cast<const bf16x8*>(vb + o);                  \
        bf16x8 af0 = *reinterpret_cast<const bf16x8*>(rb0 + o);                 \
        bf16x8 af1 = *reinterpret_cast<const bf16x8*>(rb1 + o);                 \
        bf16x8 af2 = *reinterpret_cast<const bf16x8*>(rb2 + o);                 \
        bf16x8 af3 = *reinterpret_cast<const bf16x8*>(rb3 + o);                 \
        aK0 = __builtin_amdgcn_mfma_f32_16x16x32_bf16(af0, bk, aK0, 0, 0, 0);   \
        aVp0 = __builtin_amdgcn_mfma_f32_16x16x32_bf16(af0, bv, aVp0, 0, 0, 0); \
        aK1 = __builtin_amdgcn_mfma_f32_16x16x32_bf16(af1, bk, aK1, 0, 0, 0);   \
        aVp1 = __builtin_amdgcn_mfma_f32_16x16x32_bf16(af1, bv, aVp1, 0, 0, 0); \
        aK2 = __builtin_amdgcn_mfma_f32_16x16x32_bf16(af2, bk, aK2, 0, 0, 0);   \
        aVp2 = __builtin_amdgcn_mfma_f32_16x16x32_bf16(af2, bv, aVp2, 0, 0, 0); \
        aK3 = __builtin_amdgcn_mfma_f32_16x16x32_bf16(af3, bk, aK3, 0, 0, 0);   \
        aVp3 = __builtin_amdgcn_mfma_f32_16x16x32_bf16(af3, bv, aVp3, 0, 0, 0); \
    }

#define SCOREPART(tt, s)                                                        \
    {                                                                           \
        float pr_[4];                                                           \
        _Pragma("unroll")                                                       \
        for (int i = 0; i < 4; i++) pr_[i] = row_sum16(prelu_f(aK##s[i], pa) * uw##s); \
        if (c == 0) {                                                           \
            _Pragma("unroll")                                                   \
            for (int i = 0; i < 4; i++) sp[s][(tt) & 1][rg * 4 + i][w] = pr_[i]; \
        }                                                                       \
    }

// ---------------- main: one BLOCK (8 waves) per FOUR batch rows; fused weight
// loads; mask compaction; overlapped prologue; exact defer-max softmax.
__global__ __launch_bounds__(512, 2)
void pool_main(
    const float* __restrict__ X,      // [2048,200,256]
    const int*   __restrict__ maskp,  // [2048,200] 1 = pad
    const float* __restrict__ temb,   // [2048,64]
    const float* __restrict__ Wq,     // [128,64]
    const float* __restrict__ Wker,   // [128,128]
    const float* __restrict__ ffnW,   // [256,128]
    const float* __restrict__ ffnb,   // [256]
    const float* __restrict__ prelu_a,
    const __hip_bfloat16* __restrict__ Wb,  // ws: swizzled bf16 weights [256][256]
    float* __restrict__ out)          // [2048*256] ffn, then [2048*200] attn
{
    __shared__ __hip_bfloat16 Xt[NS][2][16][256];   // 64 KB, dbuf bf16 X tiles
    __shared__ float sp[NS][2][16][8];              // 4 KB score partials
    __shared__ float arena[NS][336];                // prologue tq/Qv/uv -> scores[208]+ovec[128]
    __shared__ int   idx_lds[NS][208];              // compacted valid-row indices
    __shared__ int   nvt[NS];                       // valid count per stream

    const int tid  = threadIdx.x;
    const int w    = tid >> 6;        // wave 0..7
    const int lane = tid & 63;
    const int c    = lane & 15;
    const int rg   = lane >> 4;
    const int b0   = blockIdx.x * NS;
    const float pa = *prelu_a;
    const float inv_scale = 0.08838834764831845f;  // 1/sqrt(128)

    const int srow  = tid >> 5;       // staging row 0..15
    const int chunk = tid & 31;       // 32B chunk in row
    const int wr_off = srow * 512 + ((chunk * 16) ^ ((srow & 7) << 4));
    char* xbase = (char*)&Xt[0][0][0][0];
    const int rswz = (c & 7) << 4;

    // weight fragment bases (L2-resident, shared chip-wide and across streams)
    const char* kb = (const char*)Wb + (size_t)(16 * w + c) * 512;
    const char* vb = kb + 65536;

    // ---- prologue A: per-stream valid-row compaction (wave w handles stream w)
    if (w < NS) {
        int base = 0;
        #pragma unroll
        for (int ch = 0; ch < 4; ch++) {
            int pos = ch * 64 + lane;
            bool val = (pos < SS) && (maskp[(size_t)(b0 + w) * SS + pos] == 0);
            unsigned long long ball = __ballot(val);
            int pre = __popcll(ball & ((1ull << lane) - 1));
            if (val) idx_lds[w][base + pre] = pos;
            base += (int)__popcll(ball);
        }
        asm volatile("s_waitcnt lgkmcnt(0)" ::: "memory");
        int safe = (base > 0) ? idx_lds[w][base - 1] : 0;
        for (int j = base + lane; j < 208; j += 64) idx_lds[w][j] = safe;
        if (lane == 0) nvt[w] = base;
    }
    // temb for all 4 streams
    const int ps = tid >> 7;          // prologue stream 0..3
    const int po = tid & 127;
    if (po < DITEM) arena[ps][po] = temb[(size_t)(b0 + ps) * DITEM + po];
    __syncthreads();

    // ---- issue tile-0 gathers for ALL 4 streams NOW (prologue-only register
    // sets); their HBM latency hides under the Q/u matvecs below.
    f32x4 p0lo, p0hi, p1lo, p1hi, p2lo, p2hi, p3lo, p3hi;
    ISSUE_R(0, 0, p0lo, p0hi); ISSUE_R(0, 1, p1lo, p1hi);
    ISSUE_R(0, 2, p2lo, p2hi); ISSUE_R(0, 3, p3lo, p3hi);

    // ---- prologue B: Q = prelu(W_q @ t)   (reads arena[ps][0..63], writes
    // arena[ps][64..191] — disjoint, no inner barrier needed)
    {
        float acc = 0.f;
        #pragma unroll
        for (int d4 = 0; d4 < 16; d4++) {
            f32x4 tv = *reinterpret_cast<const f32x4*>(&arena[ps][d4 * 4]);
            f32x4 wq4 = *reinterpret_cast<const f32x4*>(Wq + (size_t)po * DITEM + d4 * 4);
            acc += wq4[0]*tv[0] + wq4[1]*tv[1] + wq4[2]*tv[2] + wq4[3]*tv[3];
        }
        arena[ps][64 + po] = prelu_f(acc, pa);
    }
    __syncthreads();

    // u = W_kernel @ Q -> arena[ps][192+po]  (reads 64..191, writes 192..319)
    {
        float acc = 0.f;
        #pragma unroll
        for (int d4 = 0; d4 < 32; d4++) {
            f32x4 qv = *reinterpret_cast<const f32x4*>(&arena[ps][64 + d4 * 4]);
            f32x4 wk4 = *reinterpret_cast<const f32x4*>(Wker + (size_t)po * AA + d4 * 4);
            acc += wk4[0]*qv[0] + wk4[1]*qv[1] + wk4[2]*qv[2] + wk4[3]*qv[3];
        }
        arena[ps][192 + po] = acc;
    }
    __syncthreads();
    const float uw0 = arena[0][192 + 16 * w + c];
    const float uw1 = arena[1][192 + 16 * w + c];
    const float uw2 = arena[2][192 + 16 * w + c];
    const float uw3 = arena[3][192 + 16 * w + c];
    const int nv0 = nvt[0], nv1 = nvt[1], nv2 = nvt[2], nv3 = nvt[3];
    int ntmax = (nv0 + 15) >> 4;
    { int n1 = (nv1 + 15) >> 4; if (n1 > ntmax) ntmax = n1; }
    { int n2 = (nv2 + 15) >> 4; if (n2 > ntmax) ntmax = n2; }
    { int n3 = (nv3 + 15) >> 4; if (n3 > ntmax) ntmax = n3; }
    if (ntmax < 1) ntmax = 1;

    // init full-length scores to -1e9 (masked/invalid positions -> exp == 0).
    if (tid < 208) {
        arena[0][tid] = -1e9f; arena[1][tid] = -1e9f;
        arena[2][tid] = -1e9f; arena[3][tid] = -1e9f;
    }

    // ---- stage tile 0 from the long-landed prologue registers
    STAGE_R(0, 0, p0lo, p0hi); STAGE_R(0, 1, p1lo, p1hi);
    STAGE_R(0, 2, p2lo, p2hi); STAGE_R(0, 3, p3lo, p3hi);
    __syncthreads();

    // ---- main loop over COMPACTED tiles: 1 barrier/tile
    float m0 = -INFINITY, l0 = 0.f, oacc0 = 0.f;
    float m1 = -INFINITY, l1 = 0.f, oacc1 = 0.f;
    float m2 = -INFINITY, l2 = 0.f, oacc2 = 0.f;
    float m3 = -INFINITY, l3 = 0.f, oacc3 = 0.f;
    f32x4 aVp0 = {0.f,0.f,0.f,0.f}, aVp1 = {0.f,0.f,0.f,0.f};
    f32x4 aVp2 = {0.f,0.f,0.f,0.f}, aVp3 = {0.f,0.f,0.f,0.f};
    f32x4 stAlo, stAhi, stBlo, stBhi;

    for (int t = 0; t < ntmax; t++) {
        const int more = (t + 1 < ntmax);

        if (more) { ISSUE_R(t + 1, 0, stAlo, stAhi); ISSUE_R(t + 1, 1, stBlo, stBhi); }

        if (t > 0) { SMFOLD(t - 1, 0); SMFOLD(t - 1, 1); SMFOLD(t - 1, 2); SMFOLD(t - 1, 3); }
        aVp0 = (f32x4){0.f,0.f,0.f,0.f}; aVp1 = (f32x4){0.f,0.f,0.f,0.f};
        aVp2 = (f32x4){0.f,0.f,0.f,0.f}; aVp3 = (f32x4){0.f,0.f,0.f,0.f};

        const char* rb0 = xbase + 0 * 16384 + (t & 1) * 8192 + c * 512;
        const char* rb1 = xbase + 1 * 16384 + (t & 1) * 8192 + c * 512;
        const char* rb2 = xbase + 2 * 16384 + (t & 1) * 8192 + c * 512;
        const char* rb3 = xbase + 3 * 16384 + (t & 1) * 8192 + c * 512;
        f32x4 aK0 = {0.f,0.f,0.f,0.f}, aK1 = {0.f,0.f,0.f,0.f};
        f32x4 aK2 = {0.f,0.f,0.f,0.f}, aK3 = {0.f,0.f,0.f,0.f};

        CHALF(0);

        if (more) {
            STAGE_R(t + 1, 0, stAlo, stAhi); ISSUE_R(t + 1, 2, stAlo, stAhi);
            STAGE_R(t + 1, 1, stBlo, stBhi); ISSUE_R(t + 1, 3, stBlo, stBhi);
        }

        CHALF(4);

        SCOREPART(t, 0); SCOREPART(t, 1); SCOREPART(t, 2); SCOREPART(t, 3);

        if (more) { STAGE_R(t + 1, 2, stAlo, stAhi); STAGE_R(t + 1, 3, stBlo, stBhi); }
        __syncthreads();
    }

    // ---- epilogue: fold last tile (sp published by final barrier)
    {
        const int tl = ntmax - 1;
        SMFOLD(tl, 0); SMFOLD(tl, 1); SMFOLD(tl, 2); SMFOLD(tl, 3);
    }

    oacc0 += __shfl_xor(oacc0, 16, 64); oacc0 += __shfl_xor(oacc0, 32, 64);
    oacc1 += __shfl_xor(oacc1, 16, 64); oacc1 += __shfl_xor(oacc1, 32, 64);
    oacc2 += __shfl_xor(oacc2, 16, 64); oacc2 += __shfl_xor(oacc2, 32, 64);
    oacc3 += __shfl_xor(oacc3, 16, 64); oacc3 += __shfl_xor(oacc3, 32, 64);
    const float invl0 = 1.0f / l0, invl1 = 1.0f / l1;
    const float invl2 = 1.0f / l2, invl3 = 1.0f / l3;
    if (lane < 16) {
        arena[0][208 + 16 * w + lane] = oacc0 * invl0;
        arena[1][208 + 16 * w + lane] = oacc1 * invl1;
        arena[2][208 + 16 * w + lane] = oacc2 * invl2;
        arena[3][208 + 16 * w + lane] = oacc3 * invl3;
    }
    __syncthreads();

    // attn outputs: scores at original positions; masked slots stayed -1e9 -> 0
    if (tid < SS) {
        out[(size_t)NB * DSEQ + (size_t)(b0 + 0) * SS + tid] = __expf(arena[0][tid] - m0) * invl0;
        out[(size_t)NB * DSEQ + (size_t)(b0 + 1) * SS + tid] = __expf(arena[1][tid] - m1) * invl1;
        out[(size_t)NB * DSEQ + (size_t)(b0 + 2) * SS + tid] = __expf(arena[2][tid] - m2) * invl2;
        out[(size_t)NB * DSEQ + (size_t)(b0 + 3) * SS + tid] = __expf(arena[3][tid] - m3) * invl3;
    }

    // FFN: thread handles output o for streams sA and sA+2 (ffnW row read once)
    {
        const int o  = tid & 255;
        const int sA = tid >> 8;       // 0 or 1
        float accA = ffnb[o], accB = accA;
        #pragma unroll 8
        for (int a4 = 0; a4 < 32; a4++) {
            f32x4 wv4 = *reinterpret_cast<const f32x4*>(ffnW + (size_t)o * AA + a4 * 4);
            f32x4 ovA = *reinterpret_cast<const f32x4*>(&arena[sA][208 + a4 * 4]);
            f32x4 ovB = *reinterpret_cast<const f32x4*>(&arena[sA + 2][208 + a4 * 4]);
            accA += wv4[0]*ovA[0] + wv4[1]*ovA[1] + wv4[2]*ovA[2] + wv4[3]*ovA[3];
            accB += wv4[0]*ovB[0] + wv4[1]*ovB[1] + wv4[2]*ovB[2] + wv4[3]*ovB[3];
        }
        out[(size_t)(b0 + sA) * DSEQ + o]     = prelu_f(accA, pa);
        out[(size_t)(b0 + sA + 2) * DSEQ + o] = prelu_f(accB, pa);
    }
}

extern "C" void kernel_launch(void* const* d_in, const int* in_sizes, int n_in,
                              void* d_out, int out_size, void* d_ws, size_t ws_size,
                              hipStream_t stream) {
    const float* X    = (const float*)d_in[0];
    const int*   mask = (const int*)  d_in[1];
    const float* temb = (const float*)d_in[2];
    const float* Wq   = (const float*)d_in[3];
    const float* Wk   = (const float*)d_in[4];
    const float* Wv   = (const float*)d_in[5];
    const float* Wker = (const float*)d_in[6];
    const float* ffnW = (const float*)d_in[7];
    const float* ffnb = (const float*)d_in[8];
    const float* pa   = (const float*)d_in[9];
    float* out = (float*)d_out;

    __hip_bfloat16* Wb = (__hip_bfloat16*)d_ws;

    prep_kernel<<<256, 256, 0, stream>>>(Wk, Wv, Wb);
    pool_main<<<NB / NS, 512, 0, stream>>>(X, mask, temb, Wq, Wker, ffnW, ffnb, pa, Wb, out);
}